// Round 2
// baseline (1058.722 us; speedup 1.0000x reference)
//
#include <hip/hip_runtime.h>
#include <cmath>

// Problem constants
#define HH    128
#define WW    128
#define CCH   256
#define BATCH 8
#define NPLANE (BATCH*CCH)          // 2048 planes
#define PLANE_ELEMS (HH*WW)         // 16384 floats per plane

// Padded LDS plane: 3-row top/bottom border, 4-col left/right border, zeros.
// Row stride 136 floats (16B-aligned). SINGLE buffer -> 72,896 B -> 2 blocks/CU.
#define TB   3
#define STR  136
#define S4   34                     // stride in float4
#define HPAD 134                    // 3 + 128 + 3
#define PLANE_LDS (HPAD*STR)        // 18224 floats = 72,896 B

// ---------------------------------------------------------------------------
// One conv pass over the plane in LDS. Thread tile: 4 wide x 16 tall.
// tx in 0..31 (col0 = 4*tx), ty in 0..7 (row0 = 16*ty).
// Register window: 7 rows x 12 floats (3x float4), padded cols 4*tx .. 4*tx+11,
// covering taps for the 4 output cols. Start col 4*tx -> a wave's 64 lanes
// spread ds_read_b128 starts over ALL 32 banks (conflict-free).
// Tap (ky,kx), output col i reads wd[(o+ky)%7][i+kx+1].
// INIT0=1: acc starts at 0 (Bx pass). INIT0=0: acc starts at accin[] (A step).
// Result written to out[] registers (64 floats = 16 rows x 4 cols).
// ---------------------------------------------------------------------------
template<int INIT0>
__device__ __forceinline__ void conv16(const float* sbuf, const float* cf,
                                       const float* accin, float* out,
                                       int tx, int ty)
{
    const int xq = tx;              // float4 index of window start
    const int y0 = ty * 16;         // padded row of first window row
    __align__(16) float wd[7][12];
    const float4* s4 = (const float4*)sbuf;

#pragma unroll
    for (int r = 0; r < 7; r++) {
        const float4* row = s4 + (y0 + r) * S4 + xq;
        float4 a = row[0], b = row[1], c = row[2];
        *(float4*)&wd[r][0] = a; *(float4*)&wd[r][4] = b; *(float4*)&wd[r][8] = c;
    }

#pragma unroll
    for (int o = 0; o < 16; o++) {
        if (o > 0) {
            const int slot = (o + 6) % 7;
            const float4* row = s4 + (y0 + o + 6) * S4 + xq;
            float4 a = row[0], b = row[1], c = row[2];
            *(float4*)&wd[slot][0] = a; *(float4*)&wd[slot][4] = b;
            *(float4*)&wd[slot][8] = c;
        }
        float a0, a1, a2, a3;
        if (INIT0) { a0 = a1 = a2 = a3 = 0.0f; }
        else { a0 = accin[o*4+0]; a1 = accin[o*4+1]; a2 = accin[o*4+2]; a3 = accin[o*4+3]; }
#pragma unroll
        for (int ky = 0; ky < 7; ky++) {
            const int s = (o + ky) % 7;
#pragma unroll
            for (int kx = 0; kx < 7; kx++) {
                const float k = cf[ky * 7 + kx];
                a0 = fmaf(wd[s][0 + kx + 1], k, a0);
                a1 = fmaf(wd[s][1 + kx + 1], k, a1);
                a2 = fmaf(wd[s][2 + kx + 1], k, a2);
                a3 = fmaf(wd[s][3 + kx + 1], k, a3);
            }
        }
        out[o*4+0] = a0; out[o*4+1] = a1; out[o*4+2] = a2; out[o*4+3] = a3;
    }
}

// Write a 16x4 register tile into the LDS plane interior.
__device__ __forceinline__ void tile_to_lds(float* sbuf, const float* v,
                                            int tx, int ty)
{
    float4* d4 = (float4*)sbuf;
    const int y0 = ty * 16;
#pragma unroll
    for (int o = 0; o < 16; o++) {
        d4[(y0 + o + TB) * S4 + tx + 1] =
            make_float4(v[o*4+0], v[o*4+1], v[o*4+2], v[o*4+3]);
    }
}

// ---------------------------------------------------------------------------
// Fused SSM kernel: one block per (b,c) plane, single LDS plane buffer,
// h_{t+1} held in registers across the compute->write barrier pair.
// ---------------------------------------------------------------------------
__global__ __launch_bounds__(256, 2) void ssm_kernel(float* planes,
                                                     const float* __restrict__ Ak,
                                                     const float* __restrict__ Bk)
{
    __shared__ float buf[PLANE_LDS];     // 72,896 B -> 2 blocks/CU
    const int p  = blockIdx.x;
    const int c  = p & (CCH - 1);
    const int t  = threadIdx.x;
    const int tx = t & 31, ty = t >> 5;

    // zero the whole buffer (borders must be 0; interior overwritten below)
    {
        float4* z = (float4*)buf;
        for (int i = t; i < PLANE_LDS / 4; i += 256)
            z[i] = make_float4(0.f, 0.f, 0.f, 0.f);
    }

    // B-kernel taps (block-uniform -> force SGPR)
    float bco[49];
#pragma unroll
    for (int i = 0; i < 49; i++) {
        float v = Bk[i * CCH + c];
        bco[i] = __uint_as_float(__builtin_amdgcn_readfirstlane(__float_as_uint(v)));
    }

    __syncthreads();

    // load x plane into interior (coalesced 16B/lane)
    const float4* gx = (const float4*)planes + (size_t)p * (PLANE_ELEMS / 4);
#pragma unroll
    for (int i = 0; i < 16; i++) {
        int idx = i * 256 + t, y = idx >> 5, xc = idx & 31;
        ((float4*)buf)[(y + TB) * S4 + xc + 1] = gx[idx];
    }
    __syncthreads();

    // Pass 1: Bx = conv(x, B) -> registers (this is also h1)
    float bx[64];
    conv16<1>(buf, bco, nullptr, bx, tx, ty);

    // A_stable taps: 0.9*tanh(A) -> SGPR
    float aco[49];
#pragma unroll
    for (int i = 0; i < 49; i++) {
        float v = 0.9f * tanhf(Ak[i * CCH + c]);
        aco[i] = __uint_as_float(__builtin_amdgcn_readfirstlane(__float_as_uint(v)));
    }

    __syncthreads();                 // all window reads of x done
    tile_to_lds(buf, bx, tx, ty);    // LDS := h1
    __syncthreads();

    // 6 intermediate steps: h_{t+1} = conv(h_t, A) + Bx
    float hn[64];
    for (int s = 0; s < 6; s++) {
        conv16<0>(buf, aco, bx, hn, tx, ty);
        __syncthreads();             // all reads of h_t done
        tile_to_lds(buf, hn, tx, ty);
        __syncthreads();             // writes visible
    }

    // final step: write h8 from registers straight to global (plane-major)
    conv16<0>(buf, aco, bx, hn, tx, ty);
    {
        float4* gout = (float4*)planes + (size_t)p * (PLANE_ELEMS / 4);
        const int y0 = ty * 16;
#pragma unroll
        for (int o = 0; o < 16; o++) {
            gout[(y0 + o) * 32 + tx] =
                make_float4(hn[o*4+0], hn[o*4+1], hn[o*4+2], hn[o*4+3]);
        }
    }
}

// ---------------------------------------------------------------------------
// NHWC -> plane-major transpose. Per batch b: M[hw=16384][c=256] -> T[c][hw].
// 64x64 tiles, float4 global access both sides, scalar LDS (pad 65 -> ~2-way).
// ---------------------------------------------------------------------------
__global__ __launch_bounds__(256) void transpose_in(const float* __restrict__ x,
                                                    float* __restrict__ xt)
{
    __shared__ float tile[64][65];
    const int p = blockIdx.x;                 // 8 * 256 * 4 = 8192 blocks
    const int b = p >> 10, rem = p & 1023, thw = rem >> 2, tc = rem & 3;
    const int t = threadIdx.x;
    const int m = t & 15, g = t >> 4;

    const size_t inbase = ((size_t)(b * 16384 + thw * 64)) * 256 + tc * 64;
#pragma unroll
    for (int i = 0; i < 4; i++) {
        int r = i * 16 + g;
        float4 v = *(const float4*)(x + inbase + (size_t)r * 256 + m * 4);
        tile[r][m * 4 + 0] = v.x; tile[r][m * 4 + 1] = v.y;
        tile[r][m * 4 + 2] = v.z; tile[r][m * 4 + 3] = v.w;
    }
    __syncthreads();
    const size_t outbase = ((size_t)(b * 256 + tc * 64)) * 16384 + thw * 64;
#pragma unroll
    for (int i = 0; i < 4; i++) {
        int cr = i * 16 + g;
        float4 v = make_float4(tile[m * 4 + 0][cr], tile[m * 4 + 1][cr],
                               tile[m * 4 + 2][cr], tile[m * 4 + 3][cr]);
        *(float4*)(xt + outbase + (size_t)cr * 16384 + m * 4) = v;
    }
}

// plane-major -> NHWC (inverse of the above)
__global__ __launch_bounds__(256) void transpose_out(const float* __restrict__ ht,
                                                     float* __restrict__ out)
{
    __shared__ float tile[64][65];
    const int p = blockIdx.x;
    const int b = p >> 10, rem = p & 1023, thw = rem >> 2, tc = rem & 3;
    const int t = threadIdx.x;
    const int m = t & 15, g = t >> 4;

    const size_t inbase = ((size_t)(b * 256 + tc * 64)) * 16384 + thw * 64;
#pragma unroll
    for (int i = 0; i < 4; i++) {
        int cr = i * 16 + g;
        float4 v = *(const float4*)(ht + inbase + (size_t)cr * 16384 + m * 4);
        tile[cr][m * 4 + 0] = v.x; tile[cr][m * 4 + 1] = v.y;
        tile[cr][m * 4 + 2] = v.z; tile[cr][m * 4 + 3] = v.w;
    }
    __syncthreads();
    const size_t outbase = ((size_t)(b * 16384 + thw * 64)) * 256 + tc * 64;
#pragma unroll
    for (int i = 0; i < 4; i++) {
        int r = i * 16 + g;
        float4 v = make_float4(tile[m * 4 + 0][r], tile[m * 4 + 1][r],
                               tile[m * 4 + 2][r], tile[m * 4 + 3][r]);
        *(float4*)(out + outbase + (size_t)r * 256 + m * 4) = v;
    }
}

extern "C" void kernel_launch(void* const* d_in, const int* in_sizes, int n_in,
                              void* d_out, int out_size, void* d_ws, size_t ws_size,
                              hipStream_t stream)
{
    (void)in_sizes; (void)n_in; (void)out_size; (void)ws_size;
    const float* x  = (const float*)d_in[0];
    const float* Ak = (const float*)d_in[1];
    const float* Bk = (const float*)d_in[2];
    float* out    = (float*)d_out;
    float* planes = (float*)d_ws;     // needs 128 MiB scratch

    transpose_in <<<8192, 256, 0, stream>>>(x, planes);
    ssm_kernel   <<<NPLANE, 256, 0, stream>>>(planes, Ak, Bk);
    transpose_out<<<8192, 256, 0, stream>>>(planes, out);
}

// Round 3
// 683.384 us; speedup vs baseline: 1.5492x; 1.5492x over previous
//
#include <hip/hip_runtime.h>
#include <cmath>

// Problem constants
#define HH    128
#define WW    128
#define CCH   256
#define BATCH 8
#define NPLANE (BATCH*CCH)          // 2048 planes
#define PLANE_ELEMS (HH*WW)         // 16384 floats per plane

// Padded LDS plane: 3-row top/bottom border, 4-col left/right border, zeros.
// Row stride 136 floats (16B-aligned).
#define TB   3
#define STR  136
#define S4   34                     // stride in float4
#define HPAD 134                    // 3 + 128 + 3
#define PLANE_LDS (HPAD*STR)        // 18224 floats = 72,896 B per buffer

// ---------------------------------------------------------------------------
// One conv pass, thread tile 4 wide x 8 tall. 512 threads/block:
// tx in 0..31 (col0 = 4*tx) -> wave's b128 starts span all 32 banks
// (R2 measured SQ_LDS_BANK_CONFLICT = 0 with this pattern).
// ty in 0..15 (row0 = 8*ty).
// Register window wd[7][12]: padded cols 4*tx .. 4*tx+11 (3x float4),
// output col j reads wd[slot][j+kx+1].
// MODE 0: Bx pass  (acc=0,   save acc -> bx, write row to dst LDS)
// MODE 1: mid step (acc=bx,  write row to dst LDS)
// MODE 2: final    (acc=bx,  write row to global plane)
// ---------------------------------------------------------------------------
template<int MODE>
__device__ __forceinline__ void conv8(const float* src, float* dstl, float4* gout,
                                      const float* cf, float* bx, int tx, int ty)
{
    const int y0 = ty * 8;          // padded row of first window row
    __align__(16) float wd[7][12];
    const float4* s4 = (const float4*)src;
    float4* d4 = (float4*)dstl;

#pragma unroll
    for (int r = 0; r < 7; r++) {
        const float4* row = s4 + (y0 + r) * S4 + tx;
        float4 a = row[0], b = row[1], c = row[2];
        *(float4*)&wd[r][0] = a; *(float4*)&wd[r][4] = b; *(float4*)&wd[r][8] = c;
    }

#pragma unroll
    for (int o = 0; o < 8; o++) {
        if (o > 0) {
            const int slot = (o + 6) % 7;
            const float4* row = s4 + (y0 + o + 6) * S4 + tx;
            float4 a = row[0], b = row[1], c = row[2];
            *(float4*)&wd[slot][0] = a; *(float4*)&wd[slot][4] = b;
            *(float4*)&wd[slot][8] = c;
        }
        float a0, a1, a2, a3;
        if (MODE == 0) { a0 = a1 = a2 = a3 = 0.0f; }
        else { a0 = bx[o*4+0]; a1 = bx[o*4+1]; a2 = bx[o*4+2]; a3 = bx[o*4+3]; }
#pragma unroll
        for (int ky = 0; ky < 7; ky++) {
            const int s = (o + ky) % 7;
#pragma unroll
            for (int kx = 0; kx < 7; kx++) {
                const float k = cf[ky * 7 + kx];
                a0 = fmaf(wd[s][kx + 1], k, a0);
                a1 = fmaf(wd[s][kx + 2], k, a1);
                a2 = fmaf(wd[s][kx + 3], k, a2);
                a3 = fmaf(wd[s][kx + 4], k, a3);
            }
        }
        if (MODE == 0) { bx[o*4+0]=a0; bx[o*4+1]=a1; bx[o*4+2]=a2; bx[o*4+3]=a3; }
        float4 v = make_float4(a0, a1, a2, a3);
        if (MODE == 2) gout[(y0 + o) * 32 + tx] = v;
        else           d4[(y0 + o + TB) * S4 + tx + 1] = v;
    }
}

// ---------------------------------------------------------------------------
// Fused SSM kernel: one 512-thread block per (b,c) plane.
// Double-buffered LDS plane (145,792 B -> 1 block/CU, 8 waves = 2/SIMD).
// Register demand ~150 (wd 84 + bx 32 + temps) -> no spill under the
// 256-VGPR cap of __launch_bounds__(512, 2).  One barrier per step.
// ---------------------------------------------------------------------------
__global__ __launch_bounds__(512, 2) void ssm_kernel(float* planes,
                                                     const float* __restrict__ Ak,
                                                     const float* __restrict__ Bk)
{
    __shared__ float buf[2 * PLANE_LDS];   // 145,792 B
    const int p  = blockIdx.x;
    const int c  = p & (CCH - 1);
    const int t  = threadIdx.x;
    const int tx = t & 31, ty = t >> 5;
    float* b0 = buf;
    float* b1 = buf + PLANE_LDS;

    // zero both buffers (borders must be 0; interiors overwritten)
    {
        float4* z = (float4*)buf;
        for (int i = t; i < 2 * PLANE_LDS / 4; i += 512)
            z[i] = make_float4(0.f, 0.f, 0.f, 0.f);
    }

    // taps: B (uniform scalar loads) and A_stable = 0.9*tanh(A) -> SGPR
    float bco[49], aco[49];
#pragma unroll
    for (int i = 0; i < 49; i++) bco[i] = Bk[i * CCH + c];
#pragma unroll
    for (int i = 0; i < 49; i++) {
        float v = 0.9f * tanhf(Ak[i * CCH + c]);
        aco[i] = __uint_as_float(__builtin_amdgcn_readfirstlane(__float_as_uint(v)));
    }
    __syncthreads();

    // load x plane into b0 interior (coalesced 16B/lane)
    const float4* gx = (const float4*)planes + (size_t)p * (PLANE_ELEMS / 4);
#pragma unroll
    for (int i = 0; i < 8; i++) {
        int idx = i * 512 + t, y = idx >> 5, xc = idx & 31;
        ((float4*)b0)[(y + TB) * S4 + xc + 1] = gx[idx];
    }
    __syncthreads();

    // h1 = Bx = conv(x, B) -> b1, and keep Bx in registers
    float bx[32];
    conv8<0>(b0, b1, nullptr, bco, bx, tx, ty);
    __syncthreads();

    // h2..h7: three ping-pong pairs (kept as a rolled loop for I$)
    for (int st = 0; st < 3; st++) {
        conv8<1>(b1, b0, nullptr, aco, bx, tx, ty);   // even h in b0
        __syncthreads();
        conv8<1>(b0, b1, nullptr, aco, bx, tx, ty);   // odd h in b1
        __syncthreads();
    }

    // final step: h8 from h7 (b1) straight to global (plane-major)
    float4* gout = (float4*)planes + (size_t)p * (PLANE_ELEMS / 4);
    conv8<2>(b1, nullptr, gout, aco, bx, tx, ty);
}

// ---------------------------------------------------------------------------
// NHWC -> plane-major transpose. Per batch b: M[hw=16384][c=256] -> T[c][hw].
// 64x64 tiles, float4 global access both sides, scalar LDS (pad 65 -> ~2-way).
// ---------------------------------------------------------------------------
__global__ __launch_bounds__(256) void transpose_in(const float* __restrict__ x,
                                                    float* __restrict__ xt)
{
    __shared__ float tile[64][65];
    const int p = blockIdx.x;                 // 8 * 256 * 4 = 8192 blocks
    const int b = p >> 10, rem = p & 1023, thw = rem >> 2, tc = rem & 3;
    const int t = threadIdx.x;
    const int m = t & 15, g = t >> 4;

    const size_t inbase = ((size_t)(b * 16384 + thw * 64)) * 256 + tc * 64;
#pragma unroll
    for (int i = 0; i < 4; i++) {
        int r = i * 16 + g;
        float4 v = *(const float4*)(x + inbase + (size_t)r * 256 + m * 4);
        tile[r][m * 4 + 0] = v.x; tile[r][m * 4 + 1] = v.y;
        tile[r][m * 4 + 2] = v.z; tile[r][m * 4 + 3] = v.w;
    }
    __syncthreads();
    const size_t outbase = ((size_t)(b * 256 + tc * 64)) * 16384 + thw * 64;
#pragma unroll
    for (int i = 0; i < 4; i++) {
        int cr = i * 16 + g;
        float4 v = make_float4(tile[m * 4 + 0][cr], tile[m * 4 + 1][cr],
                               tile[m * 4 + 2][cr], tile[m * 4 + 3][cr]);
        *(float4*)(xt + outbase + (size_t)cr * 16384 + m * 4) = v;
    }
}

// plane-major -> NHWC (inverse of the above)
__global__ __launch_bounds__(256) void transpose_out(const float* __restrict__ ht,
                                                     float* __restrict__ out)
{
    __shared__ float tile[64][65];
    const int p = blockIdx.x;
    const int b = p >> 10, rem = p & 1023, thw = rem >> 2, tc = rem & 3;
    const int t = threadIdx.x;
    const int m = t & 15, g = t >> 4;

    const size_t inbase = ((size_t)(b * 256 + tc * 64)) * 16384 + thw * 64;
#pragma unroll
    for (int i = 0; i < 4; i++) {
        int cr = i * 16 + g;
        float4 v = *(const float4*)(ht + inbase + (size_t)cr * 16384 + m * 4);
        tile[cr][m * 4 + 0] = v.x; tile[cr][m * 4 + 1] = v.y;
        tile[cr][m * 4 + 2] = v.z; tile[cr][m * 4 + 3] = v.w;
    }
    __syncthreads();
    const size_t outbase = ((size_t)(b * 16384 + thw * 64)) * 256 + tc * 64;
#pragma unroll
    for (int i = 0; i < 4; i++) {
        int r = i * 16 + g;
        float4 v = make_float4(tile[m * 4 + 0][r], tile[m * 4 + 1][r],
                               tile[m * 4 + 2][r], tile[m * 4 + 3][r]);
        *(float4*)(out + outbase + (size_t)r * 256 + m * 4) = v;
    }
}

extern "C" void kernel_launch(void* const* d_in, const int* in_sizes, int n_in,
                              void* d_out, int out_size, void* d_ws, size_t ws_size,
                              hipStream_t stream)
{
    (void)in_sizes; (void)n_in; (void)out_size; (void)ws_size;
    const float* x  = (const float*)d_in[0];
    const float* Ak = (const float*)d_in[1];
    const float* Bk = (const float*)d_in[2];
    float* out    = (float*)d_out;
    float* planes = (float*)d_ws;     // needs 128 MiB scratch

    transpose_in <<<8192, 256, 0, stream>>>(x, planes);
    ssm_kernel   <<<NPLANE, 512, 0, stream>>>(planes, Ak, Bk);
    transpose_out<<<8192, 256, 0, stream>>>(planes, out);
}

// Round 5
// 681.749 us; speedup vs baseline: 1.5529x; 1.0024x over previous
//
#include <hip/hip_runtime.h>
#include <cmath>

// Problem constants
#define HH    128
#define WW    128
#define CCH   256
#define BATCH 8
#define NPLANE (BATCH*CCH)          // 2048 planes
#define PLANE_ELEMS (HH*WW)         // 16384 floats per plane

// Padded LDS plane: 3-row top/bottom border, 4-col left/right border, zeros.
// Row stride 136 floats (16B-aligned).
#define TB   3
#define STR  136
#define S4   34                     // stride in float4
#define HPAD 134                    // 3 + 128 + 3
#define PLANE_LDS (HPAD*STR)        // 18224 floats = 72,896 B per buffer

// ---------------------------------------------------------------------------
// One conv pass, thread tile 4 wide x 8 tall, 512 threads/block.
// tx in 0..31 (col0 = 4*tx) -> wave's ds_read_b128 starts span all 32 banks
// (measured SQ_LDS_BANK_CONFLICT = 0 with this pattern).
// ty in 0..15 (row0 = 8*ty).
// Register window wd[7][12]: padded cols 4*tx .. 4*tx+11 (3x float4).
// Output col j, tap kx reads wd[slot][j+kx+1].
// MODE 0: Bx pass  (acc=0,   save acc -> bx, write row to dst LDS)
// MODE 1: mid step (acc=bx,  write row to dst LDS)
// MODE 2: final    (acc=bx,  write row to global plane)
// ---------------------------------------------------------------------------
template<int MODE>
__device__ __forceinline__ void conv8(const float* src, float* dstl, float4* gout,
                                      const float* cf, float* bx, int tx, int ty)
{
    const int y0 = ty * 8;          // padded row of first window row
    __align__(16) float wd[7][12];
    const float4* s4 = (const float4*)src;
    float4* d4 = (float4*)dstl;

#pragma unroll
    for (int r = 0; r < 7; r++) {
        const float4* row = s4 + (y0 + r) * S4 + tx;
        float4 a = row[0], b = row[1], c = row[2];
        *(float4*)&wd[r][0] = a; *(float4*)&wd[r][4] = b; *(float4*)&wd[r][8] = c;
    }

#pragma unroll
    for (int o = 0; o < 8; o++) {
        if (o > 0) {
            const int slot = (o + 6) % 7;
            const float4* row = s4 + (y0 + o + 6) * S4 + tx;
            float4 a = row[0], b = row[1], c = row[2];
            *(float4*)&wd[slot][0] = a; *(float4*)&wd[slot][4] = b;
            *(float4*)&wd[slot][8] = c;
        }
        float a0, a1, a2, a3;
        if (MODE == 0) { a0 = a1 = a2 = a3 = 0.0f; }
        else { a0 = bx[o*4+0]; a1 = bx[o*4+1]; a2 = bx[o*4+2]; a3 = bx[o*4+3]; }
#pragma unroll
        for (int ky = 0; ky < 7; ky++) {
            const int s = (o + ky) % 7;
#pragma unroll
            for (int kx = 0; kx < 7; kx++) {
                const float k = cf[ky * 7 + kx];
                a0 = fmaf(wd[s][kx + 1], k, a0);
                a1 = fmaf(wd[s][kx + 2], k, a1);
                a2 = fmaf(wd[s][kx + 3], k, a2);
                a3 = fmaf(wd[s][kx + 4], k, a3);
            }
        }
        if (MODE == 0) { bx[o*4+0]=a0; bx[o*4+1]=a1; bx[o*4+2]=a2; bx[o*4+3]=a3; }
        float4 v = make_float4(a0, a1, a2, a3);
        if (MODE == 2) gout[(y0 + o) * 32 + tx] = v;
        else           d4[(y0 + o + TB) * S4 + tx + 1] = v;
    }
}

// ---------------------------------------------------------------------------
// Fused SSM kernel: one 512-thread block per (b,c) plane.
// Double-buffered LDS plane (145,792 B -> 1 block/CU = 8 waves = 2/SIMD).
// amdgpu_waves_per_eu(2,2): LDS already caps us at 2 waves/EU, so pin the
// allocator there -> full 256-VGPR budget, no spill (R3: launch_bounds(512,2)
// alone let the allocator pick 128 VGPR + 190 MB of spill traffic).
// bco/aco lifetimes kept DISJOINT (49+49 uniform taps don't fit the ~102-SGPR
// file simultaneously; R2/R3 overlapped them and overflowed into VGPRs).
// ---------------------------------------------------------------------------
__global__ __launch_bounds__(512)
__attribute__((amdgpu_waves_per_eu(2, 2)))
void ssm_kernel(float* planes,
                const float* __restrict__ Ak,
                const float* __restrict__ Bk)
{
    __shared__ float buf[2 * PLANE_LDS];   // 145,792 B
    const int p  = blockIdx.x;
    const int c  = p & (CCH - 1);
    const int t  = threadIdx.x;
    const int tx = t & 31, ty = t >> 5;
    float* b0 = buf;
    float* b1 = buf + PLANE_LDS;

    // zero both buffers (borders must be 0; interiors overwritten)
    {
        float4* z = (float4*)buf;
        for (int i = t; i < 2 * PLANE_LDS / 4; i += 512)
            z[i] = make_float4(0.f, 0.f, 0.f, 0.f);
    }
    __syncthreads();

    // load x plane into b0 interior (coalesced 16B/lane)
    const float4* gx = (const float4*)planes + (size_t)p * (PLANE_ELEMS / 4);
#pragma unroll
    for (int i = 0; i < 8; i++) {
        int idx = i * 512 + t, y = idx >> 5, xc = idx & 31;
        ((float4*)b0)[(y + TB) * S4 + xc + 1] = gx[idx];
    }

    float bx[32];
    {
        // B taps -> SGPR (lifetime ends with pass 1)
        float bco[49];
#pragma unroll
        for (int i = 0; i < 49; i++) {
            float v = Bk[i * CCH + c];
            bco[i] = __uint_as_float(__builtin_amdgcn_readfirstlane(__float_as_uint(v)));
        }
        __syncthreads();
        // h1 = Bx = conv(x, B) -> b1, keep Bx in registers
        conv8<0>(b0, b1, nullptr, bco, bx, tx, ty);
    }

    // A_stable taps: 0.9*tanh(A) -> SGPR (loaded only after bco is dead)
    float aco[49];
#pragma unroll
    for (int i = 0; i < 49; i++) {
        float v = 0.9f * tanhf(Ak[i * CCH + c]);
        aco[i] = __uint_as_float(__builtin_amdgcn_readfirstlane(__float_as_uint(v)));
    }
    __syncthreads();                 // b1 (=h1) fully written

    // h2..h7: three ping-pong pairs
    for (int st = 0; st < 3; st++) {
        conv8<1>(b1, b0, nullptr, aco, bx, tx, ty);   // even h -> b0
        __syncthreads();
        conv8<1>(b0, b1, nullptr, aco, bx, tx, ty);   // odd h -> b1
        __syncthreads();
    }

    // final step: h8 from h7 (b1) straight to global (plane-major)
    float4* gout = (float4*)planes + (size_t)p * (PLANE_ELEMS / 4);
    conv8<2>(b1, nullptr, gout, aco, bx, tx, ty);
}

// ---------------------------------------------------------------------------
// NHWC -> plane-major transpose. Per batch b: M[hw=16384][c=256] -> T[c][hw].
// 64x64 tiles, float4 global access both sides, scalar LDS (pad 65 -> ~2-way).
// ---------------------------------------------------------------------------
__global__ __launch_bounds__(256) void transpose_in(const float* __restrict__ x,
                                                    float* __restrict__ xt)
{
    __shared__ float tile[64][65];
    const int p = blockIdx.x;                 // 8 * 256 * 4 = 8192 blocks
    const int b = p >> 10, rem = p & 1023, thw = rem >> 2, tc = rem & 3;
    const int t = threadIdx.x;
    const int m = t & 15, g = t >> 4;

    const size_t inbase = ((size_t)(b * 16384 + thw * 64)) * 256 + tc * 64;
#pragma unroll
    for (int i = 0; i < 4; i++) {
        int r = i * 16 + g;
        float4 v = *(const float4*)(x + inbase + (size_t)r * 256 + m * 4);
        tile[r][m * 4 + 0] = v.x; tile[r][m * 4 + 1] = v.y;
        tile[r][m * 4 + 2] = v.z; tile[r][m * 4 + 3] = v.w;
    }
    __syncthreads();
    const size_t outbase = ((size_t)(b * 256 + tc * 64)) * 16384 + thw * 64;
#pragma unroll
    for (int i = 0; i < 4; i++) {
        int cr = i * 16 + g;
        float4 v = make_float4(tile[m * 4 + 0][cr], tile[m * 4 + 1][cr],
                               tile[m * 4 + 2][cr], tile[m * 4 + 3][cr]);
        *(float4*)(xt + outbase + (size_t)cr * 16384 + m * 4) = v;
    }
}

// plane-major -> NHWC (inverse of the above)
__global__ __launch_bounds__(256) void transpose_out(const float* __restrict__ ht,
                                                     float* __restrict__ out)
{
    __shared__ float tile[64][65];
    const int p = blockIdx.x;
    const int b = p >> 10, rem = p & 1023, thw = rem >> 2, tc = rem & 3;
    const int t = threadIdx.x;
    const int m = t & 15, g = t >> 4;

    const size_t inbase = ((size_t)(b * 256 + tc * 64)) * 16384 + thw * 64;
#pragma unroll
    for (int i = 0; i < 4; i++) {
        int cr = i * 16 + g;
        float4 v = *(const float4*)(ht + inbase + (size_t)cr * 16384 + m * 4);
        tile[cr][m * 4 + 0] = v.x; tile[cr][m * 4 + 1] = v.y;
        tile[cr][m * 4 + 2] = v.z; tile[cr][m * 4 + 3] = v.w;
    }
    __syncthreads();
    const size_t outbase = ((size_t)(b * 16384 + thw * 64)) * 256 + tc * 64;
#pragma unroll
    for (int i = 0; i < 4; i++) {
        int r = i * 16 + g;
        float4 v = make_float4(tile[m * 4 + 0][r], tile[m * 4 + 1][r],
                               tile[m * 4 + 2][r], tile[m * 4 + 3][r]);
        *(float4*)(out + outbase + (size_t)r * 256 + m * 4) = v;
    }
}

extern "C" void kernel_launch(void* const* d_in, const int* in_sizes, int n_in,
                              void* d_out, int out_size, void* d_ws, size_t ws_size,
                              hipStream_t stream)
{
    (void)in_sizes; (void)n_in; (void)out_size; (void)ws_size;
    const float* x  = (const float*)d_in[0];
    const float* Ak = (const float*)d_in[1];
    const float* Bk = (const float*)d_in[2];
    float* out    = (float*)d_out;
    float* planes = (float*)d_ws;     // needs 128 MiB scratch

    transpose_in <<<8192, 256, 0, stream>>>(x, planes);
    ssm_kernel   <<<NPLANE, 512, 0, stream>>>(planes, Ak, Bk);
    transpose_out<<<8192, 256, 0, stream>>>(planes, out);
}